// Round 7
// baseline (150.932 us; speedup 1.0000x reference)
//
#include <hip/hip_runtime.h>

// Harness promotes float16 tensors to float32: x, scales, out are f32;
// weight_packed is int32, ONE BYTE (2 nibbles = 2 k-values) per element.
// => each lane's 8-k B-fragment (8 nibbles) is EXACTLY 4 consecutive ints
//    = one 16B load. No cross-lane weight sharing is needed anywhere.
#define M 32
#define N 11008
#define K 4096
#define NGROUPS 32
#define BN 16                 // n-rows per block
#define KSPLIT 8              // grid-level k split
#define KRANGE (K / KSPLIT)   // 512 k per block
#define KWAVE (KRANGE / 4)    // 128 k per wave = exactly ONE scale group

typedef _Float16 half8 __attribute__((ext_vector_type(8))); // 4 VGPRs
typedef _Float16 half4 __attribute__((ext_vector_type(4)));
typedef float floatx4 __attribute__((ext_vector_type(4)));

__device__ inline void gll16(const void* g, void* l) {
    __builtin_amdgcn_global_load_lds(
        (const __attribute__((address_space(1))) unsigned int*)g,
        (__attribute__((address_space(3))) unsigned int*)l, 16, 0, 0);
}

// 4 packed bytes (one per int) -> 8 f16 of (nibble - 8), exact 0x6400 trick
__device__ inline half8 unpack8(int4 wv) {
    uint4 uw; unsigned int b;
    b = (unsigned)wv.x; uw.x = ((b | (b << 12)) & 0x000F000Fu) | 0x64006400u;
    b = (unsigned)wv.y; uw.y = ((b | (b << 12)) & 0x000F000Fu) | 0x64006400u;
    b = (unsigned)wv.z; uw.z = ((b | (b << 12)) & 0x000F000Fu) | 0x64006400u;
    b = (unsigned)wv.w; uw.w = ((b | (b << 12)) & 0x000F000Fu) | 0x64006400u;
    const half8 c1032 = (half8)(_Float16)1032.0f; // 0x6408, exact
    return __builtin_bit_cast(half8, uw) - c1032; // exact (nib - 8)
}

// ---- pre-pass: x f32 -> f16 (512 KB -> 256 KB in d_ws), exact ----
__global__ __launch_bounds__(512) void xcvt_kernel(
    const float* __restrict__ x, _Float16* __restrict__ xf)
{
    int i = (blockIdx.x * 512 + threadIdx.x) * 4; // M*K = 131072 = 64*512*4
    float4 v = *(const float4*)(x + i);
    half4 h;
    h[0] = (_Float16)v.x; h[1] = (_Float16)v.y;
    h[2] = (_Float16)v.z; h[3] = (_Float16)v.w;
    *(half4*)(xf + i) = h;
}

#define WAITV(n) asm volatile("s_waitcnt vmcnt(" #n ")" ::: "memory")
#define SB() __builtin_amdgcn_sched_barrier(0)

// TLP-max streaming design. Wave-private everything: wave w owns k-slice
// [kw, kw+128) (= 1 scale group). It issues 13 VMEM ops upfront
// (FIFO: [scale, g0..g3 (gll16 weights, 1KB slots), x0..x7 (dwordx4)]),
// does ONE counted WAITV(8) (retires scale + all 4 gll16; the 8 x loads
// stay in flight, compiler inserts its own decreasing vmcnt before each
// use), then runs 8 MFMAs straight-line. No barriers until the epilogue
// reduce. LDS slot layout: gll16 writes lane's 16B at slot+lane*16; lane
// reads back the same 16B -> conflict-free ds_read_b128, zero addr math.
// 16 KB LDS + ~80 VGPR -> 7-8 blocks/CU = 28-32 waves/CU (latency hiding
// by TLP, which R0..R6 showed is the only thing that works for this op).
__global__ __launch_bounds__(256) void int4_gemm_kernel(
    const _Float16* __restrict__ xf,  // [M][K] f16 (pre-converted)
    const int* __restrict__ wp,       // [N][K/2] int32, 2 nibbles each
    const float* __restrict__ scales, // [N][NGROUPS] f32
    float* __restrict__ out)          // [M][N] f32, pre-zeroed
{
    __shared__ int wsh[4096];         // 16 KB: slot (w*4+j) = 256 ints (1 KB)

    const int t    = threadIdx.x;
    const int lane = t & 63;
    const int w    = t >> 6;          // wave id
    const int n0   = blockIdx.x * BN;
    const int ks   = blockIdx.y;
    const int col  = lane & 15;       // n-row of B / m-row of A fragments
    const int quad = lane >> 4;       // k sub-offset within fragment
    const int kw   = ks * KRANGE + w * KWAVE; // wave's contiguous 128 k

    // ---- VMEM op #0: this lane's scale (group kw/128) ----
    const float s = scales[(long)(n0 + col) * NGROUPS + ks * 4 + w];
    SB();

    // ---- VMEM #1..4: weight fragments via gll16 (4 rows x 64B coalesced
    // per row per instr; adjacent j's merge to full lines in L2) ----
    const int* gw = wp + (long)(n0 + col) * (K / 2) + (kw >> 1) + quad * 4;
    #pragma unroll
    for (int j = 0; j < 4; ++j)
        gll16(gw + j * 16, &wsh[(w * 4 + j) * 256]);
    SB();

    // ---- VMEM #5..12: x fragments (L2-resident) -> VGPRs ----
    const _Float16* gx0 = xf + (long)col * K + kw + quad * 8;
    const _Float16* gx1 = gx0 + 16 * K;
    half8 xa[4], xb[4];
    #pragma unroll
    for (int j = 0; j < 4; ++j) {
        xa[j] = *(const half8*)(gx0 + j * 32);
        xb[j] = *(const half8*)(gx1 + j * 32);
    }
    SB();

    WAITV(8);                         // retire scale + all 4 gll16; x in flight
    SB();

    // ---- compute: 4 k-steps x 2 m-tiles, fully unrolled ----
    floatx4 acc0 = {0,0,0,0}, acc1 = {0,0,0,0};
    #pragma unroll
    for (int j = 0; j < 4; ++j) {
        half8 bf = unpack8(*(const int4*)&wsh[(w * 4 + j) * 256 + lane * 4]);
        acc0 = __builtin_amdgcn_mfma_f32_16x16x32_f16(xa[j], bf, acc0, 0, 0, 0);
        acc1 = __builtin_amdgcn_mfma_f32_16x16x32_f16(xb[j], bf, acc1, 0, 0, 0);
    }

    // ---- epilogue: scale (fp32, distributes over the group sum), then
    // reduce 4 waves' k-partials in LDS, one atomic per output ----
    __syncthreads();                  // waves done reading slots (red aliases)
    float* red = (float*)wsh;         // 2048 floats = 8 KB
    #pragma unroll
    for (int r = 0; r < 4; ++r) {
        // C/D layout: col(n) = lane&15, row(m) = quad*4 + r
        red[w * 512 + (quad * 4 + r) * 16 + col]      = s * acc0[r];
        red[w * 512 + (quad * 4 + r + 16) * 16 + col] = s * acc1[r];
    }
    __syncthreads();
    #pragma unroll
    for (int i = 0; i < 2; ++i) {
        const int o = t + 256 * i;    // o = m*16 + n, 512 outputs
        const float sum = red[o] + red[512 + o] + red[1024 + o] + red[1536 + o];
        const int m = o >> 4;
        const int n = o & 15;
        atomicAdd(&out[(long)m * N + n0 + n], sum);
    }
}

extern "C" void kernel_launch(void* const* d_in, const int* in_sizes, int n_in,
                              void* d_out, int out_size, void* d_ws, size_t ws_size,
                              hipStream_t stream) {
    const float* x      = (const float*)d_in[0];
    const int* wp       = (const int*)d_in[1];
    const float* scales = (const float*)d_in[2];
    float* out          = (float*)d_out;
    _Float16* xf16      = (_Float16*)d_ws; // 256 KB

    (void)hipMemsetAsync(out, 0, (size_t)M * N * sizeof(float), stream);
    xcvt_kernel<<<dim3((M * K) / (512 * 4)), 512, 0, stream>>>(x, xf16);
    int4_gemm_kernel<<<dim3(N / BN, KSPLIT), 256, 0, stream>>>(xf16, wp, scales, out);
}

// Round 8
// 148.360 us; speedup vs baseline: 1.0173x; 1.0173x over previous
//
#include <hip/hip_runtime.h>

// Harness promotes float16 tensors to float32: x, scales, out are f32;
// weight_packed is int32, ONE BYTE (2 nibbles = 2 k-values) per element.
#define M 32
#define N 11008
#define K 4096
#define NGROUPS 32
#define BN 16                 // n-rows per block
#define KSPLIT 4              // grid-level k split
#define KRANGE (K / KSPLIT)   // 1024 k per block
#define BK 256                // k per chunk
#define NCHUNK (KRANGE / BK)  // 4
#define WPAIR 260             // ints per LDS 2-row pair: 2*128 + 4 pad
#define WTILE (8 * WPAIR)     // 2080 ints = 8.32 KB per chunk buffer

typedef _Float16 half8 __attribute__((ext_vector_type(8))); // 4 VGPRs
typedef _Float16 half4 __attribute__((ext_vector_type(4)));
typedef float floatx4 __attribute__((ext_vector_type(4)));

__device__ inline void gll16(const void* g, void* l) {
    __builtin_amdgcn_global_load_lds(
        (const __attribute__((address_space(1))) unsigned int*)g,
        (__attribute__((address_space(3))) unsigned int*)l, 16, 0, 0);
}

// 4 packed bytes -> 8 f16 of (nibble - 8), exact 0x6400 bias trick
__device__ inline half8 unpack8(int4 wv) {
    uint4 uw; unsigned int b;
    b = (unsigned)wv.x; uw.x = ((b | (b << 12)) & 0x000F000Fu) | 0x64006400u;
    b = (unsigned)wv.y; uw.y = ((b | (b << 12)) & 0x000F000Fu) | 0x64006400u;
    b = (unsigned)wv.z; uw.z = ((b | (b << 12)) & 0x000F000Fu) | 0x64006400u;
    b = (unsigned)wv.w; uw.w = ((b | (b << 12)) & 0x000F000Fu) | 0x64006400u;
    const half8 c1032 = (half8)(_Float16)1032.0f; // 0x6408, exact
    return __builtin_bit_cast(half8, uw) - c1032; // exact (nib - 8)
}

// ---- pre-pass: x f32 -> f16 (512 KB -> 256 KB in d_ws), exact ----
__global__ __launch_bounds__(512) void xcvt_kernel(
    const float* __restrict__ x, _Float16* __restrict__ xf)
{
    int i = (blockIdx.x * 512 + threadIdx.x) * 4; // M*K = 131072 = 64*512*4
    float4 v = *(const float4*)(x + i);
    half4 h;
    h[0] = (_Float16)v.x; h[1] = (_Float16)v.y;
    h[2] = (_Float16)v.z; h[3] = (_Float16)v.w;
    *(half4*)(xf + i) = h;
}

#define WAITV(n) asm volatile("s_waitcnt vmcnt(" #n ")" ::: "memory")
#define SB() __builtin_amdgcn_sched_barrier(0)

// R0 geometry (BN=16, KSPLIT=4, 4 chunks of 256k, weight staging + compute
// mapping copied verbatim) with three strict deltas:
//  1. x never touches LDS (zero cross-lane reuse): 4 half8/chunk/wave direct
//     to VGPRs, register-double-buffered by full unroll. LDS 25 -> 16.6 KB.
//  2. Weights double-buffered; stage(c+1) issued right after barrier c.
//  3. One barrier per chunk, counted WAITV(4) instead of vmcnt(0) drains.
// Count-safety (per-wave VMEM FIFO, order pinned by SB()):
//   prologue issues [scales:2, stage(0):2, x(0):4]. At iter-c top the FIFO is
//   [stage(c):2, x(c):4] (+scales, iter 0 only): WAITV(4) retires stage(c)
//   (and scales at c=0), leaving x(c) in flight for the compiler's own
//   counted waits before first VGPR use. After the barrier we issue
//   [stage(c+1):2 (SB) x(c+1):4] — gll16-before-x order is what keeps
//   WAITV(4) truthful next iteration. Buffer-parity safety: stage(c+1)
//   writes buf[(c+1)&1]; it is issued only after barrier c, when every wave
//   has finished compute(c-1) = the last reader of that parity.
__global__ __launch_bounds__(256) void int4_gemm_kernel(
    const _Float16* __restrict__ xf,  // [M][K] f16 (pre-converted)
    const int* __restrict__ wp,       // [N][K/2] int32, 2 nibbles each
    const float* __restrict__ scales, // [N][NGROUPS] f32
    float* __restrict__ out)          // [M][N] f32, pre-zeroed
{
    __shared__ int wsh[2 * WTILE];    // 16.64 KB; epilogue reduce aliases (8 KB)

    const int t    = threadIdx.x;
    const int lane = t & 63;
    const int w    = t >> 6;          // wave id: splits chunk k 4-ways
    const int n0   = blockIdx.x * BN;
    const int ks   = blockIdx.y;
    const int row  = lane & 15;       // n-row of B / m-row of A fragments
    const int quad = lane >> 4;
    const int kb   = ks * KRANGE;

    // ---- VMEM 1,2: scales (4 chunks; groups ks*8 + (w>>1) + 2c) ----
    const float* sbase = scales + (long)(n0 + row) * NGROUPS + ks * 8 + (w >> 1);
    const float4 sv0 = *(const float4*)(sbase);     // [0]=chunk0, [2]=chunk1
    const float4 sv1 = *(const float4*)(sbase + 4); // [0]=chunk2, [2]=chunk3
    SB();

    // ---- weight staging bases (R0 pattern: wave stages pairs 2w, 2w+1) ----
    const int p0 = w * 2, p1 = p0 + 1;
    const int h32 = lane >> 5;
    const int* ga = wp + (long)(n0 + 2 * p0 + h32) * (K / 2) + (kb >> 1) + (lane & 31) * 4;
    const int* gb = wp + (long)(n0 + 2 * p1 + h32) * (K / 2) + (kb >> 1) + (lane & 31) * 4;

    #define STAGE(c) {                                                   \
        gll16(ga + (c) * (BK / 2), &wsh[((c) & 1) * WTILE + p0 * WPAIR]);\
        gll16(gb + (c) * (BK / 2), &wsh[((c) & 1) * WTILE + p1 * WPAIR]);\
        SB();                                                            \
    }

    // ---- x fragment bases: wave w owns chunk-local k [w*64, w*64+64) ----
    const _Float16* gx0 = xf + (long)row * K + kb + w * 64 + quad * 8;
    const _Float16* gx1 = gx0 + 16 * K;

    half8 xa0[NCHUNK], xa1[NCHUNK], xb0[NCHUNK], xb1[NCHUNK];
    #define XLOAD(c) {                                   \
        xa0[c] = *(const half8*)(gx0 + (c) * BK);        \
        xa1[c] = *(const half8*)(gx0 + (c) * BK + 32);   \
        xb0[c] = *(const half8*)(gx1 + (c) * BK);        \
        xb1[c] = *(const half8*)(gx1 + (c) * BK + 32);   \
        SB();                                            \
    }

    // prologue: FIFO = [scales:2, stage(0):2, x(0):4]
    STAGE(0)
    XLOAD(0)

    floatx4 acc0 = {0,0,0,0}, acc1 = {0,0,0,0};

    #pragma unroll
    for (int c = 0; c < NCHUNK; ++c) {
        WAITV(4);                     // stage(c) landed (x(c) stays in flight)
        __builtin_amdgcn_s_barrier(); // all waves: buf[c&1] ready, c-1 readers done
        SB();
        if (c + 1 < NCHUNK) {
            STAGE(c + 1)              // gll16 first (keeps WAITV(4) truthful)
            XLOAD(c + 1)
        }

        const float sc = (c == 0) ? sv0.x : (c == 1) ? sv0.z
                       : (c == 2) ? sv1.x : sv1.z;
        floatx4 t0 = {0,0,0,0}, t1 = {0,0,0,0};
        #pragma unroll
        for (int kk = 0; kk < 2; ++kk) {
            // R0's verified B mapping: pair row>>1, half row&1, k = w*64+kk*32
            const int bidx = (c & 1) * WTILE + (row >> 1) * WPAIR + (row & 1) * 128
                           + w * 32 + kk * 16 + quad * 4;
            half8 b = unpack8(*(const int4*)&wsh[bidx]);
            t0 = __builtin_amdgcn_mfma_f32_16x16x32_f16(kk ? xa1[c] : xa0[c], b, t0, 0, 0, 0);
            t1 = __builtin_amdgcn_mfma_f32_16x16x32_f16(kk ? xb1[c] : xb0[c], b, t1, 0, 0, 0);
        }
        #pragma unroll
        for (int r = 0; r < 4; ++r) {
            acc0[r] += sc * t0[r];    // fp32 scale application, matches reference
            acc1[r] += sc * t1[r];
        }
    }
    #undef STAGE
    #undef XLOAD

    // ---- epilogue: reduce 4 waves' k-partials in LDS, one atomic per out ----
    __syncthreads();                  // all compute done; red aliases wsh
    float* red = (float*)wsh;         // 2048 floats = 8 KB
    #pragma unroll
    for (int r = 0; r < 4; ++r) {
        // C/D layout: col(n) = lane&15, row(m) = quad*4 + r
        red[w * 512 + (quad * 4 + r) * 16 + row]      = acc0[r];
        red[w * 512 + (quad * 4 + r + 16) * 16 + row] = acc1[r];
    }
    __syncthreads();
    #pragma unroll
    for (int i = 0; i < 2; ++i) {
        const int o = t + 256 * i;    // o = m*16 + n, 512 outputs
        const float sum = red[o] + red[512 + o] + red[1024 + o] + red[1536 + o];
        const int m = o >> 4;
        const int n = o & 15;
        atomicAdd(&out[(long)m * N + n0 + n], sum);
    }
}

extern "C" void kernel_launch(void* const* d_in, const int* in_sizes, int n_in,
                              void* d_out, int out_size, void* d_ws, size_t ws_size,
                              hipStream_t stream) {
    const float* x      = (const float*)d_in[0];
    const int* wp       = (const int*)d_in[1];
    const float* scales = (const float*)d_in[2];
    float* out          = (float*)d_out;
    _Float16* xf16      = (_Float16*)d_ws; // 256 KB

    (void)hipMemsetAsync(out, 0, (size_t)M * N * sizeof(float), stream);
    xcvt_kernel<<<dim3((M * K) / (512 * 4)), 512, 0, stream>>>(x, xf16);
    int4_gemm_kernel<<<dim3(N / BN, KSPLIT), 256, 0, stream>>>(xf16, wp, scales, out);
}